// Round 14
// baseline (916.470 us; speedup 1.0000x reference)
//
#include <hip/hip_runtime.h>
#include <hip/hip_bf16.h>

// ---------------- problem constants ----------------
#define NTOK 4096   // B*S
#define DIM  2048   // D
#define NEXP 8      // E
#define FDIM 4096   // F
#define NPAIR 8192  // NTOK * K(=2)

typedef __attribute__((ext_vector_type(4))) float     f32x4;
typedef __attribute__((ext_vector_type(8))) short     s16x8;
typedef __attribute__((ext_vector_type(4))) short     s16x4;
typedef __attribute__((ext_vector_type(8))) _Float16  f16x8;
typedef __attribute__((ext_vector_type(4))) _Float16  f16x4;

#define DEVI static __device__ __forceinline__

DEVI void gl2lds(const void* g, void* l) {
  __builtin_amdgcn_global_load_lds((const __attribute__((address_space(1))) unsigned int*)g,
                                   (__attribute__((address_space(3))) unsigned int*)l, 16, 0, 0);
}

DEVI float bf2f(unsigned short s) {
  unsigned int u = ((unsigned int)s) << 16; float f; __builtin_memcpy(&f, &u, 4); return f;
}
DEVI unsigned short f2bf(float f) {
  __hip_bfloat16 h = __float2bfloat16(f); unsigned short s; __builtin_memcpy(&s, &h, 2); return s;
}
DEVI float wredsum(float v) {
#pragma unroll
  for (int o = 32; o > 0; o >>= 1) v += __shfl_xor(v, o);
  return v;
}

// ---------------- LayerNorm + input conversions ----------------
__global__ __launch_bounds__(256) void ln_conv_kernel(
    const float* __restrict__ x, const float* __restrict__ gamma, const float* __restrict__ beta,
    _Float16* __restrict__ xh, _Float16* __restrict__ xl, unsigned short* __restrict__ xbf)
{
  int tok = blockIdx.x;
  int tid = threadIdx.x, lane = tid & 63, wv = tid >> 6;
  const float* xr = x + (size_t)tok * DIM;
  float v[8];
  *(float4*)(v)     = *(const float4*)(xr + tid * 8);
  *(float4*)(v + 4) = *(const float4*)(xr + tid * 8 + 4);
  float s = v[0]+v[1]+v[2]+v[3]+v[4]+v[5]+v[6]+v[7];
  __shared__ float red[4];
  s = wredsum(s);
  if (lane == 0) red[wv] = s;
  __syncthreads();
  float mu = (red[0]+red[1]+red[2]+red[3]) * (1.f / DIM);
  __syncthreads();
  float s2 = 0.f;
#pragma unroll
  for (int j = 0; j < 8; j++) { float d = v[j] - mu; s2 += d * d; }
  s2 = wredsum(s2);
  if (lane == 0) red[wv] = s2;
  __syncthreads();
  float var = (red[0]+red[1]+red[2]+red[3]) * (1.f / DIM);
  float rs = 1.0f / sqrtf(var + 1e-5f);

  float4 g0 = *(const float4*)(gamma + tid*8), g1 = *(const float4*)(gamma + tid*8 + 4);
  float4 b0 = *(const float4*)(beta  + tid*8), b1 = *(const float4*)(beta  + tid*8 + 4);
  float gg[8] = {g0.x,g0.y,g0.z,g0.w,g1.x,g1.y,g1.z,g1.w};
  float bb[8] = {b0.x,b0.y,b0.z,b0.w,b1.x,b1.y,b1.z,b1.w};
  f16x8 vh, vl; s16x8 vb;
#pragma unroll
  for (int j = 0; j < 8; j++) {
    float xn = (v[j] - mu) * rs * gg[j] + bb[j];
    _Float16 h = (_Float16)xn;
    vh[j] = h;
    vl[j] = (_Float16)((xn - (float)h) * 4096.f);
    vb[j] = (short)f2bf(v[j]);
  }
  *(f16x8*)(xh + (size_t)tok*DIM + tid*8) = vh;
  *(f16x8*)(xl + (size_t)tok*DIM + tid*8) = vl;
  *(s16x8*)(xbf + (size_t)tok*DIM + tid*8) = vb;
}

// ---------------- transpose + convert: fp32 [R][C] -> bf16 [C][R] (batched z) ----------------
__global__ __launch_bounds__(256) void transpose_bf16_kernel(
    const float* __restrict__ src, unsigned short* __restrict__ dst, int R, int C)
{
  src += (size_t)blockIdx.z * R * C;
  dst += (size_t)blockIdx.z * R * C;
  __shared__ float tile[64][65];
  int r0 = blockIdx.y * 64, c0 = blockIdx.x * 64;
  int tx = threadIdx.x & 15, ty = threadIdx.x >> 4;
#pragma unroll
  for (int i = 0; i < 4; i++) {
    float4 v = *(const float4*)(src + (size_t)(r0 + ty*4 + i) * C + c0 + tx*4);
    tile[ty*4+i][tx*4+0] = v.x; tile[ty*4+i][tx*4+1] = v.y;
    tile[ty*4+i][tx*4+2] = v.z; tile[ty*4+i][tx*4+3] = v.w;
  }
  __syncthreads();
#pragma unroll
  for (int i = 0; i < 4; i++) {
    int c = c0 + ty*4 + i;
    s16x4 o;
    o[0] = (short)f2bf(tile[tx*4+0][ty*4+i]); o[1] = (short)f2bf(tile[tx*4+1][ty*4+i]);
    o[2] = (short)f2bf(tile[tx*4+2][ty*4+i]); o[3] = (short)f2bf(tile[tx*4+3][ty*4+i]);
    *(s16x4*)(dst + (size_t)c * R + r0 + tx*4) = o;
  }
}

// ---------------- transpose + split: fp32 [R][C] -> fp16 hi [C][R], fp16 lo*4096 [C][R] ----------------
__global__ __launch_bounds__(256) void transpose_f16split_kernel(
    const float* __restrict__ src, _Float16* __restrict__ dh, _Float16* __restrict__ dl, int R, int C)
{
  __shared__ float tile[64][65];
  int r0 = blockIdx.y * 64, c0 = blockIdx.x * 64;
  int tx = threadIdx.x & 15, ty = threadIdx.x >> 4;
#pragma unroll
  for (int i = 0; i < 4; i++) {
    float4 v = *(const float4*)(src + (size_t)(r0 + ty*4 + i) * C + c0 + tx*4);
    tile[ty*4+i][tx*4+0] = v.x; tile[ty*4+i][tx*4+1] = v.y;
    tile[ty*4+i][tx*4+2] = v.z; tile[ty*4+i][tx*4+3] = v.w;
  }
  __syncthreads();
#pragma unroll
  for (int i = 0; i < 4; i++) {
    int c = c0 + ty*4 + i;
    f16x4 oh, ol;
#pragma unroll
    for (int j = 0; j < 4; j++) {
      float f = tile[tx*4+j][ty*4+i];
      _Float16 h = (_Float16)f;
      oh[j] = h;
      ol[j] = (_Float16)((f - (float)h) * 4096.f);
    }
    *(f16x4*)(dh + (size_t)c * R + r0 + tx*4) = oh;
    *(f16x4*)(dl + (size_t)c * R + r0 + tx*4) = ol;
  }
}

// ---------------- router GEMM v2: h = relu(xn @ rW1 + b1), split fp16 3-product, LDS dbuf ----------------
// r11 champion: BM=128 BN=64 BK=32, pad-80 layout, dbuf, fused asm fence+barrier.
#define R_TA 10240  // 128*80
#define R_TB 5120   // 64*80
#define R_BUF 30720 // R_TA*2 + R_TB*2
__global__ __launch_bounds__(256) void router_gemm_kernel(
    const _Float16* __restrict__ Ah, const _Float16* __restrict__ Al,
    const _Float16* __restrict__ Bh, const _Float16* __restrict__ Bl,
    const float* __restrict__ bias, float* __restrict__ Cout)
{
  __shared__ char lds[2 * R_BUF];
  const int K = DIM;
  int m0 = blockIdx.y * 128, n0 = blockIdx.x * 64;
  int tid = threadIdx.x, lane = tid & 63, wv = tid >> 6;
  int wm = wv >> 1, wn = wv & 1;

  const char* srcAh[3]; const char* srcAl[3];
  const char* srcBh[2]; const char* srcBl[2];
  {
    int i = 0;
    for (int c = wv; c < 10; c += 4, i++) {
      int doff = c*1024 + lane*16;
      int row = doff / 80; int b = doff - row*80; if (b >= 64) b = 0;
      srcAh[i] = (const char*)(Ah + (size_t)(m0+row)*K) + b;
      srcAl[i] = (const char*)(Al + (size_t)(m0+row)*K) + b;
    }
    i = 0;
    for (int c = wv; c < 5; c += 4, i++) {
      int doff = c*1024 + lane*16;
      int row = doff / 80; int b = doff - row*80; if (b >= 64) b = 0;
      srcBh[i] = (const char*)(Bh + (size_t)(n0+row)*K) + b;
      srcBl[i] = (const char*)(Bl + (size_t)(n0+row)*K) + b;
    }
  }

  // stage K-step kt into buffer `buf`
  auto stage = [&](int kt, int buf) {
    char* base = lds + buf * R_BUF;
    char* lAh = base;           char* lAl = base + R_TA;
    char* lBh = base + 2*R_TA;  char* lBl = base + 2*R_TA + R_TB;
    size_t ko = (size_t)kt * 64;
    int i = 0;
    for (int c = wv; c < 10; c += 4, i++) {
      gl2lds(srcAh[i] + ko, lAh + c*1024);
      gl2lds(srcAl[i] + ko, lAl + c*1024);
    }
    i = 0;
    for (int c = wv; c < 5; c += 4, i++) {
      gl2lds(srcBh[i] + ko, lBh + c*1024);
      gl2lds(srcBl[i] + ko, lBl + c*1024);
    }
  };

  f32x4 acc1[4][2], acc2[4][2];
#pragma unroll
  for (int mb = 0; mb < 4; mb++)
#pragma unroll
    for (int nb = 0; nb < 2; nb++) {
      acc1[mb][nb] = (f32x4){0.f,0.f,0.f,0.f};
      acc2[mb][nb] = (f32x4){0.f,0.f,0.f,0.f};
    }

  // prologue
  stage(0, 0);
  asm volatile("s_waitcnt vmcnt(0)\n\ts_barrier" ::: "memory");

  const int NT = K / 32;
  int cur = 0;
  for (int kt = 0; kt < NT; kt++) {
    char* base = lds + cur * R_BUF;
    char* lAh = base;           char* lAl = base + R_TA;
    char* lBh = base + 2*R_TA;  char* lBl = base + 2*R_TA + R_TB;
    if (kt + 1 < NT) stage(kt + 1, cur ^ 1);

    int kb = (lane >> 4) * 16;
    f16x8 ah[4], al[4], bh[2], bl[2];
#pragma unroll
    for (int mb = 0; mb < 4; mb++) {
      int r = wm*64 + mb*16 + (lane & 15);
      ah[mb] = *(const f16x8*)(lAh + r*80 + kb);
      al[mb] = *(const f16x8*)(lAl + r*80 + kb);
    }
#pragma unroll
    for (int nb = 0; nb < 2; nb++) {
      int r = wn*32 + nb*16 + (lane & 15);
      bh[nb] = *(const f16x8*)(lBh + r*80 + kb);
      bl[nb] = *(const f16x8*)(lBl + r*80 + kb);
    }
#pragma unroll
    for (int mb = 0; mb < 4; mb++)
#pragma unroll
      for (int nb = 0; nb < 2; nb++) {
        acc1[mb][nb] = __builtin_amdgcn_mfma_f32_16x16x32_f16(ah[mb], bh[nb], acc1[mb][nb], 0,0,0);
        acc2[mb][nb] = __builtin_amdgcn_mfma_f32_16x16x32_f16(ah[mb], bl[nb], acc2[mb][nb], 0,0,0);
        acc2[mb][nb] = __builtin_amdgcn_mfma_f32_16x16x32_f16(al[mb], bh[nb], acc2[mb][nb], 0,0,0);
      }
    // fused fence + barrier (v3-proven): my LDS reads done, my stagings landed, block barrier
    __builtin_amdgcn_sched_barrier(0);
    asm volatile("s_waitcnt lgkmcnt(0)\n\ts_waitcnt vmcnt(0)\n\ts_barrier" ::: "memory");
    __builtin_amdgcn_sched_barrier(0);
    cur ^= 1;
  }
#pragma unroll
  for (int mb = 0; mb < 4; mb++)
#pragma unroll
    for (int nb = 0; nb < 2; nb++) {
      int col = n0 + wn*32 + nb*16 + (lane & 15);
      float bv = bias[col];
#pragma unroll
      for (int r = 0; r < 4; r++) {
        int m = m0 + wm*64 + mb*16 + (lane >> 4)*4 + r;
        float hval = acc1[mb][nb][r] + acc2[mb][nb][r] * (1.f/4096.f) + bv;
        Cout[(size_t)m*DIM + col] = fmaxf(hval, 0.f);
      }
    }
}

// ---------------- router logits + softmax + top2 (one WAVE per token, no atomics) ----------------
__global__ __launch_bounds__(256) void router_logits_kernel(
    const float* __restrict__ h, const float* __restrict__ rW2, const float* __restrict__ rb2,
    float* __restrict__ probs,   // [NTOK][8]
    int* __restrict__ eid, float* __restrict__ wts)
{
  int lane = threadIdx.x & 63, wv = threadIdx.x >> 6;
  int tok = blockIdx.x * 4 + wv;
  const float* hr = h + (size_t)tok * DIM;
  float lg[8] = {0,0,0,0,0,0,0,0};
#pragma unroll
  for (int j = 0; j < 8; j++) {
    int k = j * 256 + lane * 4;
    float4 hv = *(const float4*)(hr + k);
    float hv4[4] = {hv.x, hv.y, hv.z, hv.w};
#pragma unroll
    for (int r = 0; r < 4; r++) {
      const float4* w4 = (const float4*)(rW2 + (size_t)(k + r) * NEXP);
      float4 wa = w4[0], wb = w4[1];
      lg[0] += hv4[r]*wa.x; lg[1] += hv4[r]*wa.y; lg[2] += hv4[r]*wa.z; lg[3] += hv4[r]*wa.w;
      lg[4] += hv4[r]*wb.x; lg[5] += hv4[r]*wb.y; lg[6] += hv4[r]*wb.z; lg[7] += hv4[r]*wb.w;
    }
  }
#pragma unroll
  for (int e = 0; e < 8; e++) {
#pragma unroll
    for (int o = 32; o > 0; o >>= 1) lg[e] += __shfl_xor(lg[e], o);
  }
  if (lane == 0) {
    float l[8], p[8];
    float m = -1e30f;
#pragma unroll
    for (int e = 0; e < 8; e++) { l[e] = lg[e] + rb2[e]; m = fmaxf(m, l[e]); }
    float s = 0.f;
#pragma unroll
    for (int e = 0; e < 8; e++) { p[e] = expf(l[e] - m); s += p[e]; }
    float inv = 1.f / s;
#pragma unroll
    for (int e = 0; e < 8; e++) { p[e] *= inv; probs[(size_t)tok*8 + e] = p[e]; }
    int i0 = 0;
#pragma unroll
    for (int e = 1; e < 8; e++) if (p[e] > p[i0]) i0 = e;
    int i1 = (i0 == 0) ? 1 : 0;
#pragma unroll
    for (int e = 0; e < 8; e++) if (e != i0 && p[e] > p[i1]) i1 = e;
    float denom = 1.f / (p[i0] + p[i1]);
    eid[tok*2+0] = i0; eid[tok*2+1] = i1;
    wts[tok*2+0] = p[i0]*denom; wts[tok*2+1] = p[i1]*denom;
  }
}

// ---------------- single-block deterministic counting sort + aux loss ----------------
__global__ __launch_bounds__(256) void router_sort_kernel(
    const int* __restrict__ eid, const float* __restrict__ probs,
    int* __restrict__ cnt, int* __restrict__ basep,
    int* __restrict__ tokenlist, int* __restrict__ pairslot,
    float* __restrict__ aux_out)
{
  __shared__ int hist[256][8];
  __shared__ float wsum[4][8];
  __shared__ int bl[8];
  __shared__ int lcnt[8];
  int t = threadIdx.x, lane = t & 63, wv = t >> 6;

  int me[32];
  {
    const int4* ep = (const int4*)(eid + t * 32);
#pragma unroll
    for (int q = 0; q < 8; q++) {
      int4 v = ep[q];
      me[q*4+0] = v.x; me[q*4+1] = v.y; me[q*4+2] = v.z; me[q*4+3] = v.w;
    }
  }
#pragma unroll
  for (int e = 0; e < 8; e++) {
    int ce = 0;
#pragma unroll
    for (int i = 0; i < 32; i++) ce += (me[i] == e) ? 1 : 0;
    hist[t][e] = ce;
  }

  float part[8] = {0,0,0,0,0,0,0,0};
  for (int i = 0; i < 16; i++) {
    const float4* p4 = (const float4*)(probs + (size_t)(t*16 + i) * 8);
    float4 a = p4[0], b = p4[1];
    part[0]+=a.x; part[1]+=a.y; part[2]+=a.z; part[3]+=a.w;
    part[4]+=b.x; part[5]+=b.y; part[6]+=b.z; part[7]+=b.w;
  }
#pragma unroll
  for (int e = 0; e < 8; e++) {
#pragma unroll
    for (int o = 32; o > 0; o >>= 1) part[e] += __shfl_xor(part[e], o);
  }
  if (lane == 0) {
#pragma unroll
    for (int e = 0; e < 8; e++) wsum[wv][e] = part[e];
  }
  __syncthreads();

  if (t < 8) {
    int running = 0;
    for (int i = 0; i < 256; i++) { int tmp = hist[i][t]; hist[i][t] = running; running += tmp; }
    lcnt[t] = running;
  }
  __syncthreads();
  if (t == 0) {
    int b = 0; float aux = 0.f;
#pragma unroll
    for (int e = 0; e < 8; e++) {
      int ce = lcnt[e];
      bl[e] = b; basep[e] = b; cnt[e] = ce; b += ce;
      float pm = (wsum[0][e]+wsum[1][e]+wsum[2][e]+wsum[3][e]) * (1.f / NTOK);
      aux += pm * logf(pm * 8.f + 1e-9f);
    }
    *aux_out = aux;
  }
  __syncthreads();

#pragma unroll
  for (int i = 0; i < 32; i++) {
    int e = me[i];
    int r = 0;
#pragma unroll
    for (int j = 0; j < i; j++) r += (me[j] == e) ? 1 : 0;
    int slot = bl[e] + hist[t][e] + r;
    int pair = t*32 + i;
    tokenlist[slot] = pair >> 1;
    pairslot[pair] = slot;
  }
}

// ---------------- expert grouped GEMM v9: single-buffer 32KB LDS, swizzled, high occupancy ----------------
// m97-class structure (r3's replay-validated stage->sync->compute->sync flow), with the
// proven 0-conflict swizzle (rule #21) and the champion grid (x=nt, y=e*32+mt: panel on one XCD).
// 32KB LDS -> 5 blocks/CU: implicit wave-level overlap (m114) replaces explicit dbuf.
// MODE 1: Eh = relu(Xg @ We1T + be1)  K=2048 N=4096    MODE 2: Yg = Eh @ We2T + be2  K=4096 N=2048
template<int MODE>
__global__ __launch_bounds__(256) void expert_gemm_v9(
    const unsigned short* __restrict__ Abase,
    const unsigned short* __restrict__ Bbase,   // [E][N][K] bf16
    const float* __restrict__ bias,             // [E][N]
    unsigned short* __restrict__ Cout,          // [slots][N] bf16
    const int* __restrict__ cnt, const int* __restrict__ basep,
    const int* __restrict__ tokenlist)
{
  const int K = (MODE == 1) ? DIM : FDIM;
  const int N = (MODE == 1) ? FDIM : DIM;
  __shared__ char lds[32768];
  int e = blockIdx.y >> 5, mt = blockIdx.y & 31;
  int ne = cnt[e];
  if (mt * 128 >= ne) return;
  int mbase = basep[e] + mt * 128;
  int n0 = blockIdx.x * 128;
  int tid = threadIdx.x, lane = tid & 63, wv = tid >> 6;
  int wm = wv >> 1, wn = wv & 1;

  const char* srcA[4]; const char* srcB[4];
  int sb = (((lane & 7) ^ ((lane >> 3) & 7)) << 4);
#pragma unroll
  for (int i = 0; i < 4; i++) {
    int c = wv + i*4;
    int row = c*8 + (lane >> 3);
    int slot = mbase + row; if (slot > NPAIR - 1) slot = NPAIR - 1;
    size_t arow = (MODE == 1) ? (size_t)tokenlist[slot] : (size_t)slot;
    srcA[i] = (const char*)(Abase + arow * K) + sb;
    srcB[i] = (const char*)(Bbase + ((size_t)e * N + n0 + row) * K) + sb;
  }

  f32x4 acc[4][4];
#pragma unroll
  for (int mb = 0; mb < 4; mb++)
#pragma unroll
    for (int nb = 0; nb < 4; nb++) acc[mb][nb] = (f32x4){0.f,0.f,0.f,0.f};

  const int NT = K / 64;
  int rsw = (lane & 7) << 4;
  for (int kt = 0; kt < NT; kt++) {
    size_t ko = (size_t)kt * 128;
#pragma unroll
    for (int i = 0; i < 4; i++) {
      gl2lds(srcA[i] + ko, lds + (wv + i*4)*1024);
      gl2lds(srcB[i] + ko, lds + 16384 + (wv + i*4)*1024);
    }
    __syncthreads();   // drains vmcnt(0): staged tile visible to all waves
#pragma unroll
    for (int ks = 0; ks < 2; ks++) {
      int kb = (ks*64 + (lane >> 4)*16) ^ rsw;
      s16x8 af[4], bf[4];
#pragma unroll
      for (int mb = 0; mb < 4; mb++)
        af[mb] = *(const s16x8*)(lds + (wm*64 + mb*16 + (lane & 15))*128 + kb);
#pragma unroll
      for (int nb = 0; nb < 4; nb++)
        bf[nb] = *(const s16x8*)(lds + 16384 + (wn*64 + nb*16 + (lane & 15))*128 + kb);
#pragma unroll
      for (int mb = 0; mb < 4; mb++)
#pragma unroll
        for (int nb = 0; nb < 4; nb++)
          acc[mb][nb] = __builtin_amdgcn_mfma_f32_16x16x32_bf16(af[mb], bf[nb], acc[mb][nb], 0,0,0);
    }
    __syncthreads();   // all reads done before next stage overwrites
  }

#pragma unroll
  for (int mb = 0; mb < 4; mb++)
#pragma unroll
    for (int nb = 0; nb < 4; nb++) {
      int col = n0 + wn*64 + nb*16 + (lane & 15);
      float bv = bias[(size_t)e * N + col];
#pragma unroll
      for (int r = 0; r < 4; r++) {
        int mloc = mt*128 + wm*64 + mb*16 + (lane >> 4)*4 + r;
        if (mloc < ne) {
          float v = acc[mb][nb][r] + bv;
          if (MODE == 1) v = fmaxf(v, 0.f);
          Cout[((size_t)basep[e] + mloc) * N + col] = f2bf(v);
        }
      }
    }
}

// ---------------- weighted combine of the two expert outputs per token ----------------
__global__ __launch_bounds__(256) void combine_kernel(
    const unsigned short* __restrict__ Yg, const int* __restrict__ pairslot,
    const float* __restrict__ wts, float* __restrict__ out)
{
  int tok = blockIdx.x, tid = threadIdx.x;
  int s0 = pairslot[tok*2], s1 = pairslot[tok*2+1];
  float w0 = wts[tok*2], w1 = wts[tok*2+1];
  s16x8 a = *(const s16x8*)(Yg + (size_t)s0 * DIM + tid*8);
  s16x8 b = *(const s16x8*)(Yg + (size_t)s1 * DIM + tid*8);
  float o[8];
#pragma unroll
  for (int j = 0; j < 8; j++)
    o[j] = w0 * bf2f((unsigned short)a[j]) + w1 * bf2f((unsigned short)b[j]);
  float* op = out + (size_t)tok * DIM + tid*8;
  float4 o0; o0.x=o[0]; o0.y=o[1]; o0.z=o[2]; o0.w=o[3];
  float4 o1; o1.x=o[4]; o1.y=o[5]; o1.z=o[6]; o1.w=o[7];
  *(float4*)op = o0;
  *(float4*)(op + 4) = o1;
}

// ---------------- host launcher ----------------
extern "C" void kernel_launch(void* const* d_in, const int* in_sizes, int n_in,
                              void* d_out, int out_size, void* d_ws, size_t ws_size,
                              hipStream_t stream)
{
  (void)in_sizes; (void)n_in; (void)out_size; (void)ws_size;
  const float* x    = (const float*)d_in[0];
  const float* ln_g = (const float*)d_in[1];
  const float* ln_b = (const float*)d_in[2];
  const float* rW1  = (const float*)d_in[3];
  const float* rb1  = (const float*)d_in[4];
  const float* rW2  = (const float*)d_in[5];
  const float* rb2  = (const float*)d_in[6];
  const float* We1  = (const float*)d_in[7];
  const float* be1  = (const float*)d_in[8];
  const float* We2  = (const float*)d_in[9];
  const float* be2  = (const float*)d_in[10];
  float* out = (float*)d_out;
  float* aux_out = out + (size_t)NTOK * DIM;

  char* ws = (char*)d_ws;
  size_t off = 0;
  auto alloc = [&](size_t bytes) { char* p = ws + off; off += (bytes + 255) & ~(size_t)255; return p; };

  _Float16* XH   = (_Float16*)alloc((size_t)NTOK * DIM * 2);
  _Float16* XL   = (_Float16*)alloc((size_t)NTOK * DIM * 2);
  unsigned short* XBF = (unsigned short*)alloc((size_t)NTOK * DIM * 2);
  _Float16* RW1H = (_Float16*)alloc((size_t)DIM * DIM * 2);
  _Float16* RW1L = (_Float16*)alloc((size_t)DIM * DIM * 2);
  unsigned short* WET = (unsigned short*)alloc((size_t)NEXP * FDIM * DIM * 2); // We1T then We2T
  unsigned short* EH  = (unsigned short*)alloc((size_t)(NPAIR + 128) * FDIM * 2);
  char* HY = alloc((size_t)(NPAIR + 128) * DIM * 2 > (size_t)NTOK*DIM*4
                     ? (size_t)(NPAIR + 128) * DIM * 2 : (size_t)NTOK*DIM*4);
  float* H = (float*)HY;                 // router hidden, dead before YG is written
  unsigned short* YG = (unsigned short*)HY;
  float* PROB = (float*)alloc((size_t)NTOK * 8 * 4);
  int* CNT  = (int*)alloc(256);
  int* BASE = CNT + 16;
  int* EID  = (int*)alloc((size_t)NPAIR * 4);
  float* WTS = (float*)alloc((size_t)NPAIR * 4);
  int* PAIRSLOT = (int*)alloc((size_t)NPAIR * 4);
  int* TOKLIST  = (int*)alloc((size_t)(NPAIR + 128) * 4);

  ln_conv_kernel<<<NTOK, 256, 0, stream>>>(x, ln_g, ln_b, XH, XL, XBF);
  transpose_f16split_kernel<<<dim3(DIM/64, DIM/64), 256, 0, stream>>>(rW1, RW1H, RW1L, DIM, DIM);
  // We1 [E][D][F] -> We1T [E][F][D]
  transpose_bf16_kernel<<<dim3(FDIM/64, DIM/64, NEXP), 256, 0, stream>>>(We1, WET, DIM, FDIM);
  router_gemm_kernel<<<dim3(DIM/64, NTOK/128), 256, 0, stream>>>(XH, XL, RW1H, RW1L, rb1, H);
  router_logits_kernel<<<NTOK/4, 256, 0, stream>>>(H, rW2, rb2, PROB, EID, WTS);
  router_sort_kernel<<<1, 256, 0, stream>>>(EID, PROB, CNT, BASE, TOKLIST, PAIRSLOT, aux_out);
  expert_gemm_v9<1><<<dim3(FDIM/128, NEXP*32), 256, 0, stream>>>(XBF, WET, be1, EH, CNT, BASE, TOKLIST);
  // We2 [E][F][D] -> We2T [E][D][F]  (reuses WET after GEMM1 is done)
  transpose_bf16_kernel<<<dim3(DIM/64, FDIM/64, NEXP), 256, 0, stream>>>(We2, WET, FDIM, DIM);
  expert_gemm_v9<2><<<dim3(DIM/128, NEXP*32), 256, 0, stream>>>(EH, WET, be2, YG, CNT, BASE, TOKLIST);
  combine_kernel<<<NTOK, 256, 0, stream>>>(YG, PAIRSLOT, WTS, out);
}

// Round 15
// 804.633 us; speedup vs baseline: 1.1390x; 1.1390x over previous
//
#include <hip/hip_runtime.h>
#include <hip/hip_bf16.h>

// ---------------- problem constants ----------------
#define NTOK 4096   // B*S
#define DIM  2048   // D
#define NEXP 8      // E
#define FDIM 4096   // F
#define NPAIR 8192  // NTOK * K(=2)

typedef __attribute__((ext_vector_type(4))) float     f32x4;
typedef __attribute__((ext_vector_type(8))) short     s16x8;
typedef __attribute__((ext_vector_type(4))) short     s16x4;
typedef __attribute__((ext_vector_type(8))) _Float16  f16x8;
typedef __attribute__((ext_vector_type(4))) _Float16  f16x4;

#define DEVI static __device__ __forceinline__

DEVI void gl2lds(const void* g, void* l) {
  __builtin_amdgcn_global_load_lds((const __attribute__((address_space(1))) unsigned int*)g,
                                   (__attribute__((address_space(3))) unsigned int*)l, 16, 0, 0);
}

DEVI float bf2f(unsigned short s) {
  unsigned int u = ((unsigned int)s) << 16; float f; __builtin_memcpy(&f, &u, 4); return f;
}
DEVI unsigned short f2bf(float f) {
  __hip_bfloat16 h = __float2bfloat16(f); unsigned short s; __builtin_memcpy(&s, &h, 2); return s;
}
DEVI float wredsum(float v) {
#pragma unroll
  for (int o = 32; o > 0; o >>= 1) v += __shfl_xor(v, o);
  return v;
}

// ---------------- LayerNorm + input conversions ----------------
__global__ __launch_bounds__(256) void ln_conv_kernel(
    const float* __restrict__ x, const float* __restrict__ gamma, const float* __restrict__ beta,
    _Float16* __restrict__ xh, _Float16* __restrict__ xl, unsigned short* __restrict__ xbf)
{
  int tok = blockIdx.x;
  int tid = threadIdx.x, lane = tid & 63, wv = tid >> 6;
  const float* xr = x + (size_t)tok * DIM;
  float v[8];
  *(float4*)(v)     = *(const float4*)(xr + tid * 8);
  *(float4*)(v + 4) = *(const float4*)(xr + tid * 8 + 4);
  float s = v[0]+v[1]+v[2]+v[3]+v[4]+v[5]+v[6]+v[7];
  __shared__ float red[4];
  s = wredsum(s);
  if (lane == 0) red[wv] = s;
  __syncthreads();
  float mu = (red[0]+red[1]+red[2]+red[3]) * (1.f / DIM);
  __syncthreads();
  float s2 = 0.f;
#pragma unroll
  for (int j = 0; j < 8; j++) { float d = v[j] - mu; s2 += d * d; }
  s2 = wredsum(s2);
  if (lane == 0) red[wv] = s2;
  __syncthreads();
  float var = (red[0]+red[1]+red[2]+red[3]) * (1.f / DIM);
  float rs = 1.0f / sqrtf(var + 1e-5f);

  float4 g0 = *(const float4*)(gamma + tid*8), g1 = *(const float4*)(gamma + tid*8 + 4);
  float4 b0 = *(const float4*)(beta  + tid*8), b1 = *(const float4*)(beta  + tid*8 + 4);
  float gg[8] = {g0.x,g0.y,g0.z,g0.w,g1.x,g1.y,g1.z,g1.w};
  float bb[8] = {b0.x,b0.y,b0.z,b0.w,b1.x,b1.y,b1.z,b1.w};
  f16x8 vh, vl; s16x8 vb;
#pragma unroll
  for (int j = 0; j < 8; j++) {
    float xn = (v[j] - mu) * rs * gg[j] + bb[j];
    _Float16 h = (_Float16)xn;
    vh[j] = h;
    vl[j] = (_Float16)((xn - (float)h) * 4096.f);
    vb[j] = (short)f2bf(v[j]);
  }
  *(f16x8*)(xh + (size_t)tok*DIM + tid*8) = vh;
  *(f16x8*)(xl + (size_t)tok*DIM + tid*8) = vl;
  *(s16x8*)(xbf + (size_t)tok*DIM + tid*8) = vb;
}

// ---------------- transpose + convert: fp32 [R][C] -> bf16 [C][R] (batched z) ----------------
__global__ __launch_bounds__(256) void transpose_bf16_kernel(
    const float* __restrict__ src, unsigned short* __restrict__ dst, int R, int C)
{
  src += (size_t)blockIdx.z * R * C;
  dst += (size_t)blockIdx.z * R * C;
  __shared__ float tile[64][65];
  int r0 = blockIdx.y * 64, c0 = blockIdx.x * 64;
  int tx = threadIdx.x & 15, ty = threadIdx.x >> 4;
#pragma unroll
  for (int i = 0; i < 4; i++) {
    float4 v = *(const float4*)(src + (size_t)(r0 + ty*4 + i) * C + c0 + tx*4);
    tile[ty*4+i][tx*4+0] = v.x; tile[ty*4+i][tx*4+1] = v.y;
    tile[ty*4+i][tx*4+2] = v.z; tile[ty*4+i][tx*4+3] = v.w;
  }
  __syncthreads();
#pragma unroll
  for (int i = 0; i < 4; i++) {
    int c = c0 + ty*4 + i;
    s16x4 o;
    o[0] = (short)f2bf(tile[tx*4+0][ty*4+i]); o[1] = (short)f2bf(tile[tx*4+1][ty*4+i]);
    o[2] = (short)f2bf(tile[tx*4+2][ty*4+i]); o[3] = (short)f2bf(tile[tx*4+3][ty*4+i]);
    *(s16x4*)(dst + (size_t)c * R + r0 + tx*4) = o;
  }
}

// ---------------- transpose + split: fp32 [R][C] -> fp16 hi [C][R], fp16 lo*4096 [C][R] ----------------
__global__ __launch_bounds__(256) void transpose_f16split_kernel(
    const float* __restrict__ src, _Float16* __restrict__ dh, _Float16* __restrict__ dl, int R, int C)
{
  __shared__ float tile[64][65];
  int r0 = blockIdx.y * 64, c0 = blockIdx.x * 64;
  int tx = threadIdx.x & 15, ty = threadIdx.x >> 4;
#pragma unroll
  for (int i = 0; i < 4; i++) {
    float4 v = *(const float4*)(src + (size_t)(r0 + ty*4 + i) * C + c0 + tx*4);
    tile[ty*4+i][tx*4+0] = v.x; tile[ty*4+i][tx*4+1] = v.y;
    tile[ty*4+i][tx*4+2] = v.z; tile[ty*4+i][tx*4+3] = v.w;
  }
  __syncthreads();
#pragma unroll
  for (int i = 0; i < 4; i++) {
    int c = c0 + ty*4 + i;
    f16x4 oh, ol;
#pragma unroll
    for (int j = 0; j < 4; j++) {
      float f = tile[tx*4+j][ty*4+i];
      _Float16 h = (_Float16)f;
      oh[j] = h;
      ol[j] = (_Float16)((f - (float)h) * 4096.f);
    }
    *(f16x4*)(dh + (size_t)c * R + r0 + tx*4) = oh;
    *(f16x4*)(dl + (size_t)c * R + r0 + tx*4) = ol;
  }
}

// ---------------- router GEMM v2: h = relu(xn @ rW1 + b1), split fp16 3-product, LDS dbuf ----------------
// r11 champion: BM=128 BN=64 BK=32, pad-80 layout, dbuf, fused asm fence+barrier.
#define R_TA 10240  // 128*80
#define R_TB 5120   // 64*80
#define R_BUF 30720 // R_TA*2 + R_TB*2
__global__ __launch_bounds__(256) void router_gemm_kernel(
    const _Float16* __restrict__ Ah, const _Float16* __restrict__ Al,
    const _Float16* __restrict__ Bh, const _Float16* __restrict__ Bl,
    const float* __restrict__ bias, float* __restrict__ Cout)
{
  __shared__ char lds[2 * R_BUF];
  const int K = DIM;
  int m0 = blockIdx.y * 128, n0 = blockIdx.x * 64;
  int tid = threadIdx.x, lane = tid & 63, wv = tid >> 6;
  int wm = wv >> 1, wn = wv & 1;

  const char* srcAh[3]; const char* srcAl[3];
  const char* srcBh[2]; const char* srcBl[2];
  {
    int i = 0;
    for (int c = wv; c < 10; c += 4, i++) {
      int doff = c*1024 + lane*16;
      int row = doff / 80; int b = doff - row*80; if (b >= 64) b = 0;
      srcAh[i] = (const char*)(Ah + (size_t)(m0+row)*K) + b;
      srcAl[i] = (const char*)(Al + (size_t)(m0+row)*K) + b;
    }
    i = 0;
    for (int c = wv; c < 5; c += 4, i++) {
      int doff = c*1024 + lane*16;
      int row = doff / 80; int b = doff - row*80; if (b >= 64) b = 0;
      srcBh[i] = (const char*)(Bh + (size_t)(n0+row)*K) + b;
      srcBl[i] = (const char*)(Bl + (size_t)(n0+row)*K) + b;
    }
  }

  // stage K-step kt into buffer `buf`
  auto stage = [&](int kt, int buf) {
    char* base = lds + buf * R_BUF;
    char* lAh = base;           char* lAl = base + R_TA;
    char* lBh = base + 2*R_TA;  char* lBl = base + 2*R_TA + R_TB;
    size_t ko = (size_t)kt * 64;
    int i = 0;
    for (int c = wv; c < 10; c += 4, i++) {
      gl2lds(srcAh[i] + ko, lAh + c*1024);
      gl2lds(srcAl[i] + ko, lAl + c*1024);
    }
    i = 0;
    for (int c = wv; c < 5; c += 4, i++) {
      gl2lds(srcBh[i] + ko, lBh + c*1024);
      gl2lds(srcBl[i] + ko, lBl + c*1024);
    }
  };

  f32x4 acc1[4][2], acc2[4][2];
#pragma unroll
  for (int mb = 0; mb < 4; mb++)
#pragma unroll
    for (int nb = 0; nb < 2; nb++) {
      acc1[mb][nb] = (f32x4){0.f,0.f,0.f,0.f};
      acc2[mb][nb] = (f32x4){0.f,0.f,0.f,0.f};
    }

  // prologue
  stage(0, 0);
  asm volatile("s_waitcnt vmcnt(0)\n\ts_barrier" ::: "memory");

  const int NT = K / 32;
  int cur = 0;
  for (int kt = 0; kt < NT; kt++) {
    char* base = lds + cur * R_BUF;
    char* lAh = base;           char* lAl = base + R_TA;
    char* lBh = base + 2*R_TA;  char* lBl = base + 2*R_TA + R_TB;
    if (kt + 1 < NT) stage(kt + 1, cur ^ 1);

    int kb = (lane >> 4) * 16;
    f16x8 ah[4], al[4], bh[2], bl[2];
#pragma unroll
    for (int mb = 0; mb < 4; mb++) {
      int r = wm*64 + mb*16 + (lane & 15);
      ah[mb] = *(const f16x8*)(lAh + r*80 + kb);
      al[mb] = *(const f16x8*)(lAl + r*80 + kb);
    }
#pragma unroll
    for (int nb = 0; nb < 2; nb++) {
      int r = wn*32 + nb*16 + (lane & 15);
      bh[nb] = *(const f16x8*)(lBh + r*80 + kb);
      bl[nb] = *(const f16x8*)(lBl + r*80 + kb);
    }
#pragma unroll
    for (int mb = 0; mb < 4; mb++)
#pragma unroll
      for (int nb = 0; nb < 2; nb++) {
        acc1[mb][nb] = __builtin_amdgcn_mfma_f32_16x16x32_f16(ah[mb], bh[nb], acc1[mb][nb], 0,0,0);
        acc2[mb][nb] = __builtin_amdgcn_mfma_f32_16x16x32_f16(ah[mb], bl[nb], acc2[mb][nb], 0,0,0);
        acc2[mb][nb] = __builtin_amdgcn_mfma_f32_16x16x32_f16(al[mb], bh[nb], acc2[mb][nb], 0,0,0);
      }
    // fused fence + barrier (v3-proven): my LDS reads done, my stagings landed, block barrier
    __builtin_amdgcn_sched_barrier(0);
    asm volatile("s_waitcnt lgkmcnt(0)\n\ts_waitcnt vmcnt(0)\n\ts_barrier" ::: "memory");
    __builtin_amdgcn_sched_barrier(0);
    cur ^= 1;
  }
#pragma unroll
  for (int mb = 0; mb < 4; mb++)
#pragma unroll
    for (int nb = 0; nb < 2; nb++) {
      int col = n0 + wn*32 + nb*16 + (lane & 15);
      float bv = bias[col];
#pragma unroll
      for (int r = 0; r < 4; r++) {
        int m = m0 + wm*64 + mb*16 + (lane >> 4)*4 + r;
        float hval = acc1[mb][nb][r] + acc2[mb][nb][r] * (1.f/4096.f) + bv;
        Cout[(size_t)m*DIM + col] = fmaxf(hval, 0.f);
      }
    }
}

// ---------------- router logits + softmax + top2 (one WAVE per token, no atomics) ----------------
__global__ __launch_bounds__(256) void router_logits_kernel(
    const float* __restrict__ h, const float* __restrict__ rW2, const float* __restrict__ rb2,
    float* __restrict__ probs,   // [NTOK][8]
    int* __restrict__ eid, float* __restrict__ wts)
{
  int lane = threadIdx.x & 63, wv = threadIdx.x >> 6;
  int tok = blockIdx.x * 4 + wv;
  const float* hr = h + (size_t)tok * DIM;
  float lg[8] = {0,0,0,0,0,0,0,0};
#pragma unroll
  for (int j = 0; j < 8; j++) {
    int k = j * 256 + lane * 4;
    float4 hv = *(const float4*)(hr + k);
    float hv4[4] = {hv.x, hv.y, hv.z, hv.w};
#pragma unroll
    for (int r = 0; r < 4; r++) {
      const float4* w4 = (const float4*)(rW2 + (size_t)(k + r) * NEXP);
      float4 wa = w4[0], wb = w4[1];
      lg[0] += hv4[r]*wa.x; lg[1] += hv4[r]*wa.y; lg[2] += hv4[r]*wa.z; lg[3] += hv4[r]*wa.w;
      lg[4] += hv4[r]*wb.x; lg[5] += hv4[r]*wb.y; lg[6] += hv4[r]*wb.z; lg[7] += hv4[r]*wb.w;
    }
  }
#pragma unroll
  for (int e = 0; e < 8; e++) {
#pragma unroll
    for (int o = 32; o > 0; o >>= 1) lg[e] += __shfl_xor(lg[e], o);
  }
  if (lane == 0) {
    float l[8], p[8];
    float m = -1e30f;
#pragma unroll
    for (int e = 0; e < 8; e++) { l[e] = lg[e] + rb2[e]; m = fmaxf(m, l[e]); }
    float s = 0.f;
#pragma unroll
    for (int e = 0; e < 8; e++) { p[e] = expf(l[e] - m); s += p[e]; }
    float inv = 1.f / s;
#pragma unroll
    for (int e = 0; e < 8; e++) { p[e] *= inv; probs[(size_t)tok*8 + e] = p[e]; }
    int i0 = 0;
#pragma unroll
    for (int e = 1; e < 8; e++) if (p[e] > p[i0]) i0 = e;
    int i1 = (i0 == 0) ? 1 : 0;
#pragma unroll
    for (int e = 0; e < 8; e++) if (e != i0 && p[e] > p[i1]) i1 = e;
    float denom = 1.f / (p[i0] + p[i1]);
    eid[tok*2+0] = i0; eid[tok*2+1] = i1;
    wts[tok*2+0] = p[i0]*denom; wts[tok*2+1] = p[i1]*denom;
  }
}

// ---------------- single-block deterministic counting sort + aux loss ----------------
__global__ __launch_bounds__(256) void router_sort_kernel(
    const int* __restrict__ eid, const float* __restrict__ probs,
    int* __restrict__ cnt, int* __restrict__ basep,
    int* __restrict__ tokenlist, int* __restrict__ pairslot,
    float* __restrict__ aux_out)
{
  __shared__ int hist[256][8];
  __shared__ float wsum[4][8];
  __shared__ int bl[8];
  __shared__ int lcnt[8];
  int t = threadIdx.x, lane = t & 63, wv = t >> 6;

  int me[32];
  {
    const int4* ep = (const int4*)(eid + t * 32);
#pragma unroll
    for (int q = 0; q < 8; q++) {
      int4 v = ep[q];
      me[q*4+0] = v.x; me[q*4+1] = v.y; me[q*4+2] = v.z; me[q*4+3] = v.w;
    }
  }
#pragma unroll
  for (int e = 0; e < 8; e++) {
    int ce = 0;
#pragma unroll
    for (int i = 0; i < 32; i++) ce += (me[i] == e) ? 1 : 0;
    hist[t][e] = ce;
  }

  float part[8] = {0,0,0,0,0,0,0,0};
  for (int i = 0; i < 16; i++) {
    const float4* p4 = (const float4*)(probs + (size_t)(t*16 + i) * 8);
    float4 a = p4[0], b = p4[1];
    part[0]+=a.x; part[1]+=a.y; part[2]+=a.z; part[3]+=a.w;
    part[4]+=b.x; part[5]+=b.y; part[6]+=b.z; part[7]+=b.w;
  }
#pragma unroll
  for (int e = 0; e < 8; e++) {
#pragma unroll
    for (int o = 32; o > 0; o >>= 1) part[e] += __shfl_xor(part[e], o);
  }
  if (lane == 0) {
#pragma unroll
    for (int e = 0; e < 8; e++) wsum[wv][e] = part[e];
  }
  __syncthreads();

  if (t < 8) {
    int running = 0;
    for (int i = 0; i < 256; i++) { int tmp = hist[i][t]; hist[i][t] = running; running += tmp; }
    lcnt[t] = running;
  }
  __syncthreads();
  if (t == 0) {
    int b = 0; float aux = 0.f;
#pragma unroll
    for (int e = 0; e < 8; e++) {
      int ce = lcnt[e];
      bl[e] = b; basep[e] = b; cnt[e] = ce; b += ce;
      float pm = (wsum[0][e]+wsum[1][e]+wsum[2][e]+wsum[3][e]) * (1.f / NTOK);
      aux += pm * logf(pm * 8.f + 1e-9f);
    }
    *aux_out = aux;
  }
  __syncthreads();

#pragma unroll
  for (int i = 0; i < 32; i++) {
    int e = me[i];
    int r = 0;
#pragma unroll
    for (int j = 0; j < i; j++) r += (me[j] == e) ? 1 : 0;
    int slot = bl[e] + hist[t][e] + r;
    int pair = t*32 + i;
    tokenlist[slot] = pair >> 1;
    pairslot[pair] = slot;
  }
}

// ---------------- expert grouped GEMM v3 (champion, 4x replay-validated) ----------------
// 128x128, BK=64, static 64KB LDS dbuf, swizzled staging (rule #21), fused asm fence+barrier.
// Grid (x=nt, y=e*32+mt): linear_id%8 = x%8 -> all 32 mt-blocks of a B panel on one XCD.
// MODE 1: Eh = relu(Xg @ We1T + be1)  K=2048 N=4096    MODE 2: Yg = Eh @ We2T + be2  K=4096 N=2048
template<int MODE>
__global__ __launch_bounds__(256, 2) void expert_gemm_v3(
    const unsigned short* __restrict__ Abase,
    const unsigned short* __restrict__ Bbase,   // [E][N][K] bf16
    const float* __restrict__ bias,             // [E][N]
    unsigned short* __restrict__ Cout,          // [slots][N] bf16
    const int* __restrict__ cnt, const int* __restrict__ basep,
    const int* __restrict__ tokenlist)
{
  const int K = (MODE == 1) ? DIM : FDIM;
  const int N = (MODE == 1) ? FDIM : DIM;
  __shared__ char lds[65536];
  int e = blockIdx.y >> 5, mt = blockIdx.y & 31;
  int ne = cnt[e];
  if (mt * 128 >= ne) return;
  int mbase = basep[e] + mt * 128;
  int n0 = blockIdx.x * 128;
  int tid = threadIdx.x, lane = tid & 63, wv = tid >> 6;
  int wm = wv >> 1, wn = wv & 1;

  const char* srcA[4]; const char* srcB[4];
  int sb = (((lane & 7) ^ ((lane >> 3) & 7)) << 4);
#pragma unroll
  for (int i = 0; i < 4; i++) {
    int c = wv + i*4;
    int row = c*8 + (lane >> 3);
    int slot = mbase + row; if (slot > NPAIR - 1) slot = NPAIR - 1;
    size_t arow = (MODE == 1) ? (size_t)tokenlist[slot] : (size_t)slot;
    srcA[i] = (const char*)(Abase + arow * K) + sb;
    srcB[i] = (const char*)(Bbase + ((size_t)e * N + n0 + row) * K) + sb;
  }

  f32x4 acc[4][4];
#pragma unroll
  for (int mb = 0; mb < 4; mb++)
#pragma unroll
    for (int nb = 0; nb < 4; nb++) acc[mb][nb] = (f32x4){0.f,0.f,0.f,0.f};

  // prologue: stage K-tile 0 into buf0
#pragma unroll
  for (int i = 0; i < 4; i++) {
    gl2lds(srcA[i], lds + (wv + i*4)*1024);
    gl2lds(srcB[i], lds + 16384 + (wv + i*4)*1024);
  }
  asm volatile("s_waitcnt vmcnt(0)\n\ts_barrier" ::: "memory");

  const int NT = K / 64;
  int rsw = (lane & 7) << 4;
  int cur = 0;
  for (int kt = 0; kt < NT; kt++) {
    char* cA = lds + cur*32768;
    char* cB = cA + 16384;
    if (kt + 1 < NT) {
      char* nA = lds + (cur^1)*32768;
      char* nB = nA + 16384;
      size_t ko = (size_t)(kt + 1) * 128;
#pragma unroll
      for (int i = 0; i < 4; i++) {
        gl2lds(srcA[i] + ko, nA + (wv + i*4)*1024);
        gl2lds(srcB[i] + ko, nB + (wv + i*4)*1024);
      }
    }
#pragma unroll
    for (int ks = 0; ks < 2; ks++) {
      int kb = (ks*64 + (lane >> 4)*16) ^ rsw;
      s16x8 af[4], bf[4];
#pragma unroll
      for (int mb = 0; mb < 4; mb++)
        af[mb] = *(const s16x8*)(cA + (wm*64 + mb*16 + (lane & 15))*128 + kb);
#pragma unroll
      for (int nb = 0; nb < 4; nb++)
        bf[nb] = *(const s16x8*)(cB + (wn*64 + nb*16 + (lane & 15))*128 + kb);
#pragma unroll
      for (int mb = 0; mb < 4; mb++)
#pragma unroll
        for (int nb = 0; nb < 4; nb++)
          acc[mb][nb] = __builtin_amdgcn_mfma_f32_16x16x32_bf16(af[mb], bf[nb], acc[mb][nb], 0,0,0);
    }
    __builtin_amdgcn_sched_barrier(0);
    asm volatile("s_waitcnt lgkmcnt(0)\n\ts_waitcnt vmcnt(0)\n\ts_barrier" ::: "memory");
    __builtin_amdgcn_sched_barrier(0);
    cur ^= 1;
  }

#pragma unroll
  for (int mb = 0; mb < 4; mb++)
#pragma unroll
    for (int nb = 0; nb < 4; nb++) {
      int col = n0 + wn*64 + nb*16 + (lane & 15);
      float bv = bias[(size_t)e * N + col];
#pragma unroll
      for (int r = 0; r < 4; r++) {
        int mloc = mt*128 + wm*64 + mb*16 + (lane >> 4)*4 + r;
        if (mloc < ne) {
          float v = acc[mb][nb][r] + bv;
          if (MODE == 1) v = fmaxf(v, 0.f);
          Cout[((size_t)basep[e] + mloc) * N + col] = f2bf(v);
        }
      }
    }
}

// ---------------- weighted combine of the two expert outputs per token ----------------
__global__ __launch_bounds__(256) void combine_kernel(
    const unsigned short* __restrict__ Yg, const int* __restrict__ pairslot,
    const float* __restrict__ wts, float* __restrict__ out)
{
  int tok = blockIdx.x, tid = threadIdx.x;
  int s0 = pairslot[tok*2], s1 = pairslot[tok*2+1];
  float w0 = wts[tok*2], w1 = wts[tok*2+1];
  s16x8 a = *(const s16x8*)(Yg + (size_t)s0 * DIM + tid*8);
  s16x8 b = *(const s16x8*)(Yg + (size_t)s1 * DIM + tid*8);
  float o[8];
#pragma unroll
  for (int j = 0; j < 8; j++)
    o[j] = w0 * bf2f((unsigned short)a[j]) + w1 * bf2f((unsigned short)b[j]);
  float* op = out + (size_t)tok * DIM + tid*8;
  float4 o0; o0.x=o[0]; o0.y=o[1]; o0.z=o[2]; o0.w=o[3];
  float4 o1; o1.x=o[4]; o1.y=o[5]; o1.z=o[6]; o1.w=o[7];
  *(float4*)op = o0;
  *(float4*)(op + 4) = o1;
}

// ---------------- host launcher ----------------
extern "C" void kernel_launch(void* const* d_in, const int* in_sizes, int n_in,
                              void* d_out, int out_size, void* d_ws, size_t ws_size,
                              hipStream_t stream)
{
  (void)in_sizes; (void)n_in; (void)out_size; (void)ws_size;
  const float* x    = (const float*)d_in[0];
  const float* ln_g = (const float*)d_in[1];
  const float* ln_b = (const float*)d_in[2];
  const float* rW1  = (const float*)d_in[3];
  const float* rb1  = (const float*)d_in[4];
  const float* rW2  = (const float*)d_in[5];
  const float* rb2  = (const float*)d_in[6];
  const float* We1  = (const float*)d_in[7];
  const float* be1  = (const float*)d_in[8];
  const float* We2  = (const float*)d_in[9];
  const float* be2  = (const float*)d_in[10];
  float* out = (float*)d_out;
  float* aux_out = out + (size_t)NTOK * DIM;

  char* ws = (char*)d_ws;
  size_t off = 0;
  auto alloc = [&](size_t bytes) { char* p = ws + off; off += (bytes + 255) & ~(size_t)255; return p; };

  _Float16* XH   = (_Float16*)alloc((size_t)NTOK * DIM * 2);
  _Float16* XL   = (_Float16*)alloc((size_t)NTOK * DIM * 2);
  unsigned short* XBF = (unsigned short*)alloc((size_t)NTOK * DIM * 2);
  _Float16* RW1H = (_Float16*)alloc((size_t)DIM * DIM * 2);
  _Float16* RW1L = (_Float16*)alloc((size_t)DIM * DIM * 2);
  unsigned short* WET = (unsigned short*)alloc((size_t)NEXP * FDIM * DIM * 2); // We1T then We2T
  unsigned short* EH  = (unsigned short*)alloc((size_t)(NPAIR + 128) * FDIM * 2);
  char* HY = alloc((size_t)(NPAIR + 128) * DIM * 2 > (size_t)NTOK*DIM*4
                     ? (size_t)(NPAIR + 128) * DIM * 2 : (size_t)NTOK*DIM*4);
  float* H = (float*)HY;                 // router hidden, dead before YG is written
  unsigned short* YG = (unsigned short*)HY;
  float* PROB = (float*)alloc((size_t)NTOK * 8 * 4);
  int* CNT  = (int*)alloc(256);
  int* BASE = CNT + 16;
  int* EID  = (int*)alloc((size_t)NPAIR * 4);
  float* WTS = (float*)alloc((size_t)NPAIR * 4);
  int* PAIRSLOT = (int*)alloc((size_t)NPAIR * 4);
  int* TOKLIST  = (int*)alloc((size_t)(NPAIR + 128) * 4);

  ln_conv_kernel<<<NTOK, 256, 0, stream>>>(x, ln_g, ln_b, XH, XL, XBF);
  transpose_f16split_kernel<<<dim3(DIM/64, DIM/64), 256, 0, stream>>>(rW1, RW1H, RW1L, DIM, DIM);
  // We1 [E][D][F] -> We1T [E][F][D]
  transpose_bf16_kernel<<<dim3(FDIM/64, DIM/64, NEXP), 256, 0, stream>>>(We1, WET, DIM, FDIM);
  router_gemm_kernel<<<dim3(DIM/64, NTOK/128), 256, 0, stream>>>(XH, XL, RW1H, RW1L, rb1, H);
  router_logits_kernel<<<NTOK/4, 256, 0, stream>>>(H, rW2, rb2, PROB, EID, WTS);
  router_sort_kernel<<<1, 256, 0, stream>>>(EID, PROB, CNT, BASE, TOKLIST, PAIRSLOT, aux_out);
  expert_gemm_v3<1><<<dim3(FDIM/128, NEXP*32), 256, 0, stream>>>(XBF, WET, be1, EH, CNT, BASE, TOKLIST);
  // We2 [E][F][D] -> We2T [E][D][F]  (reuses WET after GEMM1 is done)
  transpose_bf16_kernel<<<dim3(DIM/64, FDIM/64, NEXP), 256, 0, stream>>>(We2, WET, FDIM, DIM);
  expert_gemm_v3<2><<<dim3(DIM/128, NEXP*32), 256, 0, stream>>>(EH, WET, be2, YG, CNT, BASE, TOKLIST);
  combine_kernel<<<NTOK, 256, 0, stream>>>(YG, PAIRSLOT, WTS, out);
}